// Round 14
// baseline (407.733 us; speedup 1.0000x reference)
//
#include <hip/hip_runtime.h>
#include <stdint.h>

typedef unsigned short u16;
typedef unsigned int   u32;
typedef __bf16 bf16x8 __attribute__((ext_vector_type(8)));
typedef __bf16 bf16x2 __attribute__((ext_vector_type(2)));
typedef float  f32x4  __attribute__((ext_vector_type(4)));
typedef float  f32x16 __attribute__((ext_vector_type(16)));
typedef u16    u16x4  __attribute__((ext_vector_type(4)));
typedef u16    u16x8  __attribute__((ext_vector_type(8)));
typedef u32    u32x4  __attribute__((ext_vector_type(4)));

#define DEV __device__ __forceinline__
#define AS1(p) ((const __attribute__((address_space(1))) void*)(p))
#define AS3(p) ((__attribute__((address_space(3))) void*)(p))

DEV u16 f2bf(float f){ return __builtin_bit_cast(u16, (__bf16)f); }
DEV float bf2f(u16 h){ return __uint_as_float(((u32)h) << 16); }
DEV u32 pack2bf(float a, float b){
  bf16x2 t; t[0] = (__bf16)a; t[1] = (__bf16)b;
  return __builtin_bit_cast(u32, t);
}
// v_permlane32_swap_b32: a.hi <-> b.lo  (gfx950)
DEV void pswap(u32 &a, u32 &b){
  asm volatile("v_permlane32_swap_b32 %0, %1" : "+v"(a), "+v"(b));
}

#define BARX() __builtin_amdgcn_s_barrier()
#define LGKM0() do{ asm volatile("s_waitcnt lgkmcnt(0)" ::: "memory"); \
                    __builtin_amdgcn_sched_barrier(0); }while(0)

// ---------------- cast kernels ----------------
__global__ __launch_bounds__(256) void k_cast_qk(const float* __restrict__ Q,
    const float* __restrict__ K, u16* __restrict__ Qb, u16* __restrict__ Kb){
  const float* s = blockIdx.y ? K : Q;
  u16* d = blockIdx.y ? Kb : Qb;
  size_t i = ((size_t)blockIdx.x * 256 + threadIdx.x) * 8;
  f32x4 a = *(const f32x4*)(s + i);
  f32x4 b = *(const f32x4*)(s + i + 4);
  u16x8 o;
  o[0]=f2bf(a[0]); o[1]=f2bf(a[1]); o[2]=f2bf(a[2]); o[3]=f2bf(a[3]);
  o[4]=f2bf(b[0]); o[5]=f2bf(b[1]); o[6]=f2bf(b[2]); o[7]=f2bf(b[3]);
  *(u16x8*)(d + i) = o;
}

__global__ __launch_bounds__(256) void k_cast_w(const float* __restrict__ W0,
    const float* __restrict__ W1, const float* __restrict__ W2,
    const float* __restrict__ W3, u16* __restrict__ dst){
  const float* s = (blockIdx.y == 0) ? W0 : (blockIdx.y == 1) ? W1 :
                   (blockIdx.y == 2) ? W2 : W3;
  size_t i = ((size_t)blockIdx.x * 256 + threadIdx.x) * 8;
  u16* d = dst + (size_t)blockIdx.y * 1048576u + i;
  f32x4 a = *(const f32x4*)(s + i);
  f32x4 b = *(const f32x4*)(s + i + 4);
  u16x8 o;
  o[0]=f2bf(a[0]); o[1]=f2bf(a[1]); o[2]=f2bf(a[2]); o[3]=f2bf(a[3]);
  o[4]=f2bf(b[0]); o[5]=f2bf(b[1]); o[6]=f2bf(b[2]); o[7]=f2bf(b[3]);
  *(u16x8*)d = o;
}

// ---------------- GEMM (256x256 tile, 8-phase, counted vmcnt) ----------------
// C[m,n] = sum_k A[m,k]*W[n,k].  8 waves (2M x 4N), BK=64, 2 K-tiles/iter.
// EPI=0: bf16 out N=1024. EPI=1: f32 relu+bias+residual. EPI=2: N=2048 dual:
//   n<1024 -> kproj[m][n];  n>=1024 -> vT[(b*16+h)*64+d][key] (fused transpose,
//   key=m&511 contiguous per lane -> u16x4 stores).
template<int EPI>
__global__ __launch_bounds__(512, 2) void k_gemm8(const u16* __restrict__ A,
    const u16* __restrict__ Bw, void* __restrict__ Cout, void* __restrict__ Cout2,
    const u16* __restrict__ Xres, const float* __restrict__ bo)
{
  __shared__ u16 Asl[2][256][64];
  __shared__ u16 Bsl[2][256][64];
  const int tid = threadIdx.x, lane = tid & 63, w = tid >> 6;
  const int wm = w >> 2, wn = w & 3;
  constexpr int NT = (EPI == 2) ? 8 : 4;
  const int bid = blockIdx.x;
  const int xcd = bid & 7, jt = bid >> 3;
  const int m0 = (xcd*8 + jt/NT) * 256;
  const int n0 = (jt%NT) * 256;
  const int fr = lane & 15, fgi = lane >> 4;
  const int sgs = (lane & 7) ^ (lane >> 3);     // pre-swizzled source granule
  const u16* Abase = A  + (size_t)m0*1024 + sgs*8;
  const u16* Bbase = Bw + (size_t)n0*1024 + sgs*8;

  f32x4 acc[8][4];
  #pragma unroll
  for (int i=0;i<8;++i)
    #pragma unroll
    for (int q=0;q<4;++q)
      #pragma unroll
      for (int e=0;e<4;++e) acc[i][q][e] = 0.f;

  // stage one half-tile (128 rows x 64 cols = 2 loads/thread), LDS dest linear
  auto stA = [&](int buf, int h, int kt){
    #pragma unroll
    for (int r=0;r<2;++r){
      const int rb = h*128 + r*64 + w*8;
      __builtin_amdgcn_global_load_lds(
        AS1(Abase + (size_t)(rb + (lane>>3))*1024 + kt*64),
        AS3(&Asl[buf][rb][0]), 16, 0, 0);
    }
  };
  auto stB = [&](int buf, int h, int kt){
    #pragma unroll
    for (int r=0;r<2;++r){
      const int rb = h*128 + r*64 + w*8;
      __builtin_amdgcn_global_load_lds(
        AS1(Bbase + (size_t)(rb + (lane>>3))*1024 + kt*64),
        AS3(&Bsl[buf][rb][0]), 16, 0, 0);
    }
  };
  // register subtile loads (swizzled reads, proven conflict-free pattern)
  auto ldA = [&](bf16x8* af, int buf, int mh){       // 8 x ds_read_b128
    #pragma unroll
    for (int mi=0;mi<4;++mi)
      #pragma unroll
      for (int ks=0;ks<2;++ks)
        af[mi*2+ks] = *(const bf16x8*)&Asl[buf][wm*128 + mh*64 + mi*16 + fr]
                                          [(((ks*4+fgi)^(fr&7))*8)];
  };
  auto ldB = [&](bf16x8* bq, int buf, int nh){       // 4 x ds_read_b128
    #pragma unroll
    for (int ni=0;ni<2;++ni)
      #pragma unroll
      for (int ks=0;ks<2;++ks)
        bq[ni*2+ks] = *(const bf16x8*)&Bsl[buf][wn*64 + nh*32 + ni*16 + fr]
                                           [(((ks*4+fgi)^(fr&7))*8)];
  };

#define MMAQ(AF, BF, MH, NH) do{                                             \
    __builtin_amdgcn_s_setprio(1);                                           \
    _Pragma("unroll")                                                        \
    for (int mi=0;mi<4;++mi){                                                \
      _Pragma("unroll")                                                      \
      for (int ni=0;ni<2;++ni){                                              \
        _Pragma("unroll")                                                    \
        for (int ks=0;ks<2;++ks)                                             \
          acc[(MH)*4+mi][(NH)*2+ni] = __builtin_amdgcn_mfma_f32_16x16x32_bf16( \
            (AF)[mi*2+ks], (BF)[ni*2+ks], acc[(MH)*4+mi][(NH)*2+ni], 0,0,0); \
      }}                                                                     \
    __builtin_amdgcn_s_setprio(0); }while(0)

  // prologue: buf0 <- K-tile0 (all 4 halves), buf1 <- K-tile1 B-halves
  stA(0,0,0); stA(0,1,0); stB(0,0,0); stB(0,1,0);
  stB(1,0,1); stB(1,1,1);
  asm volatile("s_waitcnt vmcnt(4)" ::: "memory");   // buf0 complete
  BARX();

  bf16x8 af[8], bq0[4], bq1[4];
  #pragma unroll 1
  for (int t=0; t<8; ++t){
    const int klo = 2*t, khi = 2*t+1;
    const bool pf = (t < 7);
    // P1: read A-mh0,B-nh0 (buf0); stage buf1-Ah0 (khi)
    ldA(af, 0, 0); ldB(bq0, 0, 0);
    stA(1, 0, khi);
    BARX(); LGKM0(); MMAQ(af, bq0, 0, 0); BARX();
    // P2: read B-nh1 (buf0); stage buf1-Ah1 (khi)
    ldB(bq1, 0, 1);
    stA(1, 1, khi);
    BARX(); LGKM0(); MMAQ(af, bq1, 0, 1); BARX();
    // P3: read A-mh1 (buf0); stage buf0-Bh0 (klo+2)
    ldA(af, 0, 1);
    if (pf) stB(0, 0, klo+2);
    BARX(); LGKM0(); MMAQ(af, bq1, 1, 1); BARX();
    // P4: regs only; stage buf0-Bh1 (klo+2); counted vmcnt covers buf1
    if (pf) stB(0, 1, klo+2);
    BARX(); MMAQ(af, bq0, 1, 0);
    if (pf) asm volatile("s_waitcnt vmcnt(4)" ::: "memory");
    else    asm volatile("s_waitcnt vmcnt(0)" ::: "memory");
    BARX();
    // P5: read A-mh0,B-nh0 (buf1); stage buf0-Ah0 (klo+2)
    ldA(af, 1, 0); ldB(bq0, 1, 0);
    if (pf) stA(0, 0, klo+2);
    BARX(); LGKM0(); MMAQ(af, bq0, 0, 0); BARX();
    // P6: read B-nh1 (buf1); stage buf0-Ah1 (klo+2)
    ldB(bq1, 1, 1);
    if (pf) stA(0, 1, klo+2);
    BARX(); LGKM0(); MMAQ(af, bq1, 0, 1); BARX();
    // P7: read A-mh1 (buf1); stage buf1-Bh0 (khi+2)
    ldA(af, 1, 1);
    if (pf) stB(1, 0, khi+2);
    BARX(); LGKM0(); MMAQ(af, bq1, 1, 1); BARX();
    // P8: regs only; stage buf1-Bh1 (khi+2); counted vmcnt covers buf0
    if (pf) stB(1, 1, khi+2);
    BARX(); MMAQ(af, bq0, 1, 0);
    if (pf) asm volatile("s_waitcnt vmcnt(4)" ::: "memory");
    BARX();
  }
#undef MMAQ

  const int cr = fgi * 4;
  if (EPI == 2 && n0 >= 1024){
    // fused V transpose: vT[(b*1024 + hd)][key], key = m & 511 (4 consecutive)
    u16* vTd = (u16*)Cout2;
    #pragma unroll
    for (int mf=0; mf<8; ++mf){
      const int mb = m0 + wm*128 + mf*16 + cr;
      const int bb = mb >> 9, key = mb & 511;
      #pragma unroll
      for (int nf=0; nf<4; ++nf){
        const int hd = (n0 - 1024) + wn*64 + nf*16 + fr;
        u16x4 ov;
        #pragma unroll
        for (int e=0;e<4;++e) ov[e] = f2bf(acc[mf][nf][e]);
        *(u16x4*)(vTd + (size_t)(bb*1024 + hd)*512 + key) = ov;
      }
    }
  } else {
    #pragma unroll
    for (int mf=0; mf<8; ++mf){
      #pragma unroll
      for (int nf=0; nf<4; ++nf){
        const int n = n0 + wn*64 + nf*16 + fr;
        #pragma unroll
        for (int e=0;e<4;++e){
          const int m = m0 + wm*128 + mf*16 + cr + e;
          float v = acc[mf][nf][e];
          if (EPI == 1){
            float r = v + bo[n];
            r = r > 0.f ? r : 0.f;
            ((float*)Cout)[(size_t)m*1024 + n] = bf2f(Xres[(size_t)m*1024 + n]) + r;
          } else {
            ((u16*)Cout)[(size_t)m*1024 + n] = f2bf(v);
          }
        }
      }
    }
  }
}

// ---------------- fused flash attention + residual (streamed K/V) ------------
// grid = B*H*2 ; block = 256 (4 waves, 64 q-rows = 2 fragments each).
// K/V streamed in 32-key slices through a depth-4 LDS ring; counted vmcnt(4)
// + raw s_barrier per step.  4 blocks/CU co-resident (33.8KB LDS, <=128 VGPR):
// grid fits in ONE generation, latency hidden by cross-block TLP.
__global__ __launch_bounds__(256, 4) void k_attn(const u16* __restrict__ qproj,
    const u16* __restrict__ kproj, const u16* __restrict__ vT,
    const int* __restrict__ mask, float* __restrict__ O)
{
  __shared__ alignas(16) char smem[33792];
  u16* KR = (u16*)smem;              // ring: 4 x [32 key][64 d]  (16 KB)
  u16* VR = (u16*)(smem + 16384);    // ring: 4 x [64 d][32 key]  (16 KB)
  u16* mv = (u16*)(smem + 32768);    // 512 mask bf16 values (1 KB)
  // epilogue reuses smem[0,32768): 4 waves x [32 q][64 d] f32, XOR-swizzled

  const int bidl = (int)blockIdx.x;
  const int bid = (bidl & 7) * 128 + (bidl >> 3);   // XCD-contiguous, bijective
  const int qh = bid & 1, h = (bid >> 1) & 15, b = bid >> 5;
  const int tid = threadIdx.x, lane = tid & 63, w = tid >> 6;
  const int q31 = lane & 31, hi = lane >> 5;
  const float CSC = 0.04508421990278011f;   // log2(e)/32 (pre-applied to Q)

  // mask -> bf16(-8192) table
  mv[tid]       = mask[b*512 + tid]       ? 0xC600u : 0u;
  mv[tid + 256] = mask[b*512 + 256 + tid] ? 0xC600u : 0u;
  __syncthreads();

  // per-step staging: wave w stages keys [w*8,w*8+8) of K slice and
  // d-rows [w*16,w*16+16) of V^T slice. LDS dest linear; source pre-swizzled.
  auto stage = [&](int s){
    const int r = s & 3;
    {
      const int kl = w*8 + (lane >> 3);
      const int gs = (lane & 7) ^ (kl & 7);
      __builtin_amdgcn_global_load_lds(
        AS1(kproj + (size_t)(b*512 + s*32 + kl)*1024 + h*64 + gs*8),
        AS3(KR + r*2048 + w*512), 16, 0, 0);
    }
    {
      const int d = w*16 + (lane >> 2);
      const int gs = (lane & 3) ^ ((d >> 1) & 3);
      __builtin_amdgcn_global_load_lds(
        AS1(vT + (size_t)((b*16 + h)*64 + d)*512 + s*32 + gs*8),
        AS3(VR + r*2048 + w*512), 16, 0, 0);
    }
  };

  stage(0); stage(1); stage(2);   // 6 loads in flight per wave

  // Q fragments for 2 x 32 q-rows, pre-scaled by CSC
  bf16x8 qf[2][4];
  #pragma unroll
  for (int f=0;f<2;++f){
    const int qrow = qh*256 + w*64 + f*32 + q31;
    const u16* g = qproj + (size_t)(b*512 + qrow)*1024 + h*64 + hi*8;
    #pragma unroll
    for (int ss=0;ss<4;++ss){
      u16x8 raw = *(const u16x8*)(g + ss*16);
      u32x4 sc;
      #pragma unroll
      for (int e2=0;e2<4;++e2)
        sc[e2] = pack2bf(bf2f(raw[2*e2])*CSC, bf2f(raw[2*e2+1])*CSC);
      qf[f][ss] = __builtin_bit_cast(bf16x8, sc);
    }
  }
  // Qtilde extra-slice B operand: kdim0 = 1.0 for all q columns
  u32x4 qxv = {hi ? 0u : 0x3F80u, 0u, 0u, 0u};
  const bf16x8 qx = __builtin_bit_cast(bf16x8, qxv);

  f32x16 acc0[2], acc1[2];
  #pragma unroll
  for (int hh=0;hh<2;++hh)
    #pragma unroll
    for (int r=0;r<16;++r){ acc0[hh][r] = 0.f; acc1[hh][r] = 0.f; }
  float ls0a=0.f, ls0b=0.f, ls1a=0.f, ls1b=0.f;

  auto compute = [&](int s){
    const int r = s & 3;
    const int ksw = q31 & 7;
    const u16* krow = KR + r*2048 + q31*64;
    bf16x8 kf[4];
    #pragma unroll
    for (int ss=0; ss<4; ++ss)
      kf[ss] = *(const bf16x8*)&krow[(((2*ss + hi) ^ ksw) * 8)];
    const u32 e0 = (u32)mv[s*32 + q31];
    u32x4 kxv = {hi ? 0u : e0, 0u, 0u, 0u};
    const bf16x8 kx = __builtin_bit_cast(bf16x8, kxv);

    f32x16 S0, S1;
    #pragma unroll
    for (int rr=0;rr<16;++rr){ S0[rr] = 0.f; S1[rr] = 0.f; }
    __builtin_amdgcn_s_setprio(1);
    #pragma unroll
    for (int ss=0; ss<4; ++ss)
      S0 = __builtin_amdgcn_mfma_f32_32x32x16_bf16(kf[ss], qf[0][ss], S0, 0, 0, 0);
    S0 = __builtin_amdgcn_mfma_f32_32x32x16_bf16(kx, qx, S0, 0, 0, 0);
    #pragma unroll
    for (int ss=0; ss<4; ++ss)
      S1 = __builtin_amdgcn_mfma_f32_32x32x16_bf16(kf[ss], qf[1][ss], S1, 0, 0, 0);
    S1 = __builtin_amdgcn_mfma_f32_32x32x16_bf16(kx, qx, S1, 0, 0, 0);
    __builtin_amdgcn_s_setprio(0);

    u32 w0[8], w1[8];
    #pragma unroll
    for (int i2=0;i2<8;++i2){
      const float p0 = exp2f(S0[2*i2]);
      const float p1 = exp2f(S0[2*i2+1]);
      const float p2 = exp2f(S1[2*i2]);
      const float p3 = exp2f(S1[2*i2+1]);
      if (i2 & 1){ ls0b += p0 + p1; ls1b += p2 + p3; }
      else       { ls0a += p0 + p1; ls1a += p2 + p3; }
      w0[i2] = pack2bf(p0, p1);
      w1[i2] = pack2bf(p2, p3);
    }
    pswap(w0[0], w0[2]); pswap(w0[1], w0[3]);
    pswap(w0[4], w0[6]); pswap(w0[5], w0[7]);
    pswap(w1[0], w1[2]); pswap(w1[1], w1[3]);
    pswap(w1[4], w1[6]); pswap(w1[5], w1[7]);
    u32x4 a0v = {w0[0], w0[1], w0[2], w0[3]};
    u32x4 b0v = {w0[4], w0[5], w0[6], w0[7]};
    u32x4 a1v = {w1[0], w1[1], w1[2], w1[3]};
    u32x4 b1v = {w1[4], w1[5], w1[6], w1[7]};
    const bf16x8 paA0 = __builtin_bit_cast(bf16x8, a0v);
    const bf16x8 paB0 = __builtin_bit_cast(bf16x8, b0v);
    const bf16x8 paA1 = __builtin_bit_cast(bf16x8, a1v);
    const bf16x8 paB1 = __builtin_bit_cast(bf16x8, b1v);

    __builtin_amdgcn_s_setprio(1);
    #pragma unroll
    for (int hh=0;hh<2;++hh){
      const int d = hh*32 + q31;
      const int dsw = (d >> 1) & 3;
      const u16* vrow = VR + r*2048 + d*32;
      bf16x8 vf0 = *(const bf16x8*)&vrow[((hi ^ dsw) * 8)];
      bf16x8 vf1 = *(const bf16x8*)&vrow[(((2 + hi) ^ dsw) * 8)];
      acc0[hh] = __builtin_amdgcn_mfma_f32_32x32x16_bf16(vf0, paA0, acc0[hh], 0, 0, 0);
      acc0[hh] = __builtin_amdgcn_mfma_f32_32x32x16_bf16(vf1, paB0, acc0[hh], 0, 0, 0);
      acc1[hh] = __builtin_amdgcn_mfma_f32_32x32x16_bf16(vf0, paA1, acc1[hh], 0, 0, 0);
      acc1[hh] = __builtin_amdgcn_mfma_f32_32x32x16_bf16(vf1, paB1, acc1[hh], 0, 0, 0);
    }
    __builtin_amdgcn_s_setprio(0);
  };

  // main loop: counted vmcnt, stage(s+3) issued AFTER the barrier so the
  // ring slot (s+3)&3 == (s-1)&3 is provably done being read by all waves.
  #pragma unroll 1
  for (int s=0; s<14; ++s){
    asm volatile("s_waitcnt vmcnt(4)" ::: "memory");
    __builtin_amdgcn_s_barrier();
    if (s < 13) stage(s+3);
    compute(s);
  }
  asm volatile("s_waitcnt vmcnt(2)" ::: "memory");
  __builtin_amdgcn_s_barrier();
  compute(14);
  asm volatile("s_waitcnt vmcnt(0)" ::: "memory");
  __builtin_amdgcn_s_barrier();
  compute(15);

  float l0 = ls0a + ls0b;  l0 += __shfl_xor(l0, 32, 64);
  float l1 = ls1a + ls1b;  l1 += __shfl_xor(l1, 32, 64);
  const float i0 = 1.0f / l0, i1 = 1.0f / l1;

  __syncthreads();   // all waves done with KR/VR before epilogue reuse

  // epilogue: XOR-swizzled [32 q][16 granule] f32 tile per wave; store phase
  // writes one full 64B sector per row per instruction (4 lanes x 16B).
  auto epi = [&](const f32x16* accp, float inv, int f){
    float* t = (float*)smem + w*2048;
    #pragma unroll
    for (int hh=0; hh<2; ++hh)
      #pragma unroll
      for (int rq=0; rq<4; ++rq){
        const int g = (2*rq + hi + 8*hh) ^ (q31 & 15);
        f32x4 v4;
        #pragma unroll
        for (int e=0;e<4;++e) v4[e] = accp[hh][rq*4 + e] * inv;
        *(f32x4*)&t[(q31*16 + g)*4] = v4;
      }
    __syncthreads();
    const int row16 = lane >> 2, c4 = lane & 3;
    #pragma unroll
    for (int rr=0; rr<2; ++rr){
      const int q = rr*16 + row16;
      const int grow = qh*256 + w*64 + f*32 + q;
      const size_t gbase = (size_t)(b*512 + grow)*1024 + h*64;
      #pragma unroll
      for (int j=0; j<4; ++j){
        const int g = (j*4 + c4) ^ (q & 15);
        f32x4 v4 = *(const f32x4*)&t[(q*16 + g)*4];
        u16x4 qres = *(const u16x4*)(qproj + gbase + j*16 + c4*4);
        f32x4 o4;
        #pragma unroll
        for (int e=0;e<4;++e) o4[e] = v4[e] + bf2f(qres[e]);
        *(f32x4*)(O + gbase + j*16 + c4*4) = o4;
      }
    }
    __syncthreads();
  };
  epi(acc0, i0, 0);
  epi(acc1, i1, 1);
}

// ---------------- LayerNorm: one wave per row, 4 rows per block --------------
template<int OUT_BF16>
__global__ __launch_bounds__(256) void k_ln(const float* __restrict__ X,
    const float* __restrict__ gam, const float* __restrict__ bet,
    void* __restrict__ out)
{
  const int row = blockIdx.x*4 + (threadIdx.x >> 6);
  const int lane = threadIdx.x & 63;
  const float* xr = X + (size_t)row*1024 + lane*4;
  f32x4 v[4];
  float s = 0.f, ss = 0.f;
  #pragma unroll
  for (int j=0;j<4;++j){
    v[j] = *(const f32x4*)(xr + j*256);
    #pragma unroll
    for (int e=0;e<4;++e){ s += v[j][e]; ss += v[j][e]*v[j][e]; }
  }
  #pragma unroll
  for (int o=32; o>0; o>>=1){ s += __shfl_xor(s, o, 64); ss += __shfl_xor(ss, o, 64); }
  const float mu  = s * 0.0009765625f;
  const float var = ss * 0.0009765625f - mu*mu;
  const float rs  = rsqrtf(var + 1e-5f);
  #pragma unroll
  for (int j=0;j<4;++j){
    f32x4 gg = *(const f32x4*)(gam + j*256 + lane*4);
    f32x4 bb = *(const f32x4*)(bet + j*256 + lane*4);
    f32x4 o;
    #pragma unroll
    for (int e=0;e<4;++e) o[e] = (v[j][e]-mu)*rs*gg[e] + bb[e];
    if (OUT_BF16){
      u16x4 ob;
      #pragma unroll
      for (int e=0;e<4;++e) ob[e] = f2bf(o[e]);
      *(u16x4*)((u16*)out + (size_t)row*1024 + j*256 + lane*4) = ob;
    } else {
      *(f32x4*)((float*)out + (size_t)row*1024 + j*256 + lane*4) = o;
    }
  }
}

// ---------------- launch -----------------------------------------------------
extern "C" void kernel_launch(void* const* d_in, const int* in_sizes, int n_in,
                              void* d_out, int out_size, void* d_ws, size_t ws_size,
                              hipStream_t stream)
{
  const float* Q  = (const float*)d_in[0];
  const float* K  = (const float*)d_in[1];
  const int*   Mk = (const int*)d_in[2];
  const float* Wq = (const float*)d_in[3];
  const float* Wk = (const float*)d_in[4];
  const float* Wv = (const float*)d_in[5];
  const float* Wo = (const float*)d_in[6];
  const float* bo = (const float*)d_in[7];
  const float* g0 = (const float*)d_in[8];
  const float* b0 = (const float*)d_in[9];
  const float* g1 = (const float*)d_in[10];
  const float* b1 = (const float*)d_in[11];

  char* ws = (char*)d_ws;
  u16* qproj = (u16*)(ws);
  u16* kproj = (u16*)(ws + 33554432u);
  u16* Qb    = (u16*)(ws + 100663296u);
  u16* vTb   = (u16*)(ws + 100663296u);   // reuses Qb after GEMM-q
  u16* Kb    = (u16*)(ws + 134217728u);
  u16* Wb    = (u16*)(ws + 167772160u);
  u16* Xln   = qproj;                      // reuses qproj after attention
  float* Yb  = (float*)(ws + 33554432u);   // reuses kproj region after attention
  float* Ob  = (float*)d_out;              // pre-LN0 O lives in d_out

  k_cast_qk<<<dim3(8192,2),256,0,stream>>>(Q, K, Qb, Kb);
  k_cast_w <<<dim3(512,4), 256,0,stream>>>(Wq, Wk, Wv, Wo, Wb);
  k_gemm8<0><<<256,512,0,stream>>>(Qb, Wb, (void*)qproj, nullptr, nullptr, nullptr);
  k_gemm8<2><<<512,512,0,stream>>>(Kb, Wb + 1048576, (void*)kproj, (void*)vTb, nullptr, nullptr);
  k_attn   <<<1024,256,0,stream>>>(qproj, kproj, vTb, Mk, Ob);
  k_ln<1>  <<<4096,256,0,stream>>>(Ob, g0, b0, (void*)Xln);
  k_gemm8<1><<<256,512,0,stream>>>(Xln, Wb + 3145728, (void*)Yb, nullptr, Xln, bo);
  k_ln<0>  <<<4096,256,0,stream>>>(Yb, g1, b1, d_out);
}

// Round 15
// 289.921 us; speedup vs baseline: 1.4064x; 1.4064x over previous
//
#include <hip/hip_runtime.h>
#include <stdint.h>

typedef unsigned short u16;
typedef unsigned int   u32;
typedef __bf16 bf16x8 __attribute__((ext_vector_type(8)));
typedef __bf16 bf16x2 __attribute__((ext_vector_type(2)));
typedef float  f32x4  __attribute__((ext_vector_type(4)));
typedef float  f32x16 __attribute__((ext_vector_type(16)));
typedef u16    u16x4  __attribute__((ext_vector_type(4)));
typedef u16    u16x8  __attribute__((ext_vector_type(8)));
typedef u32    u32x4  __attribute__((ext_vector_type(4)));

#define DEV __device__ __forceinline__
#define AS1(p) ((const __attribute__((address_space(1))) void*)(p))
#define AS3(p) ((__attribute__((address_space(3))) void*)(p))

DEV u16 f2bf(float f){ return __builtin_bit_cast(u16, (__bf16)f); }
DEV float bf2f(u16 h){ return __uint_as_float(((u32)h) << 16); }
DEV u32 pack2bf(float a, float b){
  bf16x2 t; t[0] = (__bf16)a; t[1] = (__bf16)b;
  return __builtin_bit_cast(u32, t);
}
// v_permlane32_swap_b32: a.hi <-> b.lo  (gfx950)
DEV void pswap(u32 &a, u32 &b){
  asm volatile("v_permlane32_swap_b32 %0, %1" : "+v"(a), "+v"(b));
}

#define BARX() __builtin_amdgcn_s_barrier()
#define LGKM0() do{ asm volatile("s_waitcnt lgkmcnt(0)" ::: "memory"); \
                    __builtin_amdgcn_sched_barrier(0); }while(0)

// ---------------- cast kernels ----------------
__global__ __launch_bounds__(256) void k_cast_qk(const float* __restrict__ Q,
    const float* __restrict__ K, u16* __restrict__ Qb, u16* __restrict__ Kb){
  const float* s = blockIdx.y ? K : Q;
  u16* d = blockIdx.y ? Kb : Qb;
  size_t i = ((size_t)blockIdx.x * 256 + threadIdx.x) * 8;
  f32x4 a = *(const f32x4*)(s + i);
  f32x4 b = *(const f32x4*)(s + i + 4);
  u16x8 o;
  o[0]=f2bf(a[0]); o[1]=f2bf(a[1]); o[2]=f2bf(a[2]); o[3]=f2bf(a[3]);
  o[4]=f2bf(b[0]); o[5]=f2bf(b[1]); o[6]=f2bf(b[2]); o[7]=f2bf(b[3]);
  *(u16x8*)(d + i) = o;
}

__global__ __launch_bounds__(256) void k_cast_w(const float* __restrict__ W0,
    const float* __restrict__ W1, const float* __restrict__ W2,
    const float* __restrict__ W3, u16* __restrict__ dst){
  const float* s = (blockIdx.y == 0) ? W0 : (blockIdx.y == 1) ? W1 :
                   (blockIdx.y == 2) ? W2 : W3;
  size_t i = ((size_t)blockIdx.x * 256 + threadIdx.x) * 8;
  u16* d = dst + (size_t)blockIdx.y * 1048576u + i;
  f32x4 a = *(const f32x4*)(s + i);
  f32x4 b = *(const f32x4*)(s + i + 4);
  u16x8 o;
  o[0]=f2bf(a[0]); o[1]=f2bf(a[1]); o[2]=f2bf(a[2]); o[3]=f2bf(a[3]);
  o[4]=f2bf(b[0]); o[5]=f2bf(b[1]); o[6]=f2bf(b[2]); o[7]=f2bf(b[3]);
  *(u16x8*)d = o;
}

// ---------------- GEMM (256x256 tile, 8-phase, counted vmcnt) ----------------
// C[m,n] = sum_k A[m,k]*W[n,k].  8 waves (2M x 4N), BK=64, 2 K-tiles/iter.
// EPI=0: bf16 out N=1024. EPI=1: f32 relu+bias+residual. EPI=2: N=2048 dual:
//   n<1024 -> kproj[m][n];  n>=1024 -> fused V transpose via per-wave LDS
//   staging tile -> contiguous 256B-row stores to vT[(b*16+h)*64+d][key].
template<int EPI>
__global__ __launch_bounds__(512, 2) void k_gemm8(const u16* __restrict__ A,
    const u16* __restrict__ Bw, void* __restrict__ Cout, void* __restrict__ Cout2,
    const u16* __restrict__ Xres, const float* __restrict__ bo)
{
  __shared__ u16 Asl[2][256][64];
  __shared__ u16 Bsl[2][256][64];
  const int tid = threadIdx.x, lane = tid & 63, w = tid >> 6;
  const int wm = w >> 2, wn = w & 3;
  constexpr int NT = (EPI == 2) ? 8 : 4;
  const int bid = blockIdx.x;
  const int xcd = bid & 7, jt = bid >> 3;
  const int m0 = (xcd*8 + jt/NT) * 256;
  const int n0 = (jt%NT) * 256;
  const int fr = lane & 15, fgi = lane >> 4;
  const int sgs = (lane & 7) ^ (lane >> 3);     // pre-swizzled source granule
  const u16* Abase = A  + (size_t)m0*1024 + sgs*8;
  const u16* Bbase = Bw + (size_t)n0*1024 + sgs*8;

  f32x4 acc[8][4];
  #pragma unroll
  for (int i=0;i<8;++i)
    #pragma unroll
    for (int q=0;q<4;++q)
      #pragma unroll
      for (int e=0;e<4;++e) acc[i][q][e] = 0.f;

  // stage one half-tile (128 rows x 64 cols = 2 loads/thread), LDS dest linear
  auto stA = [&](int buf, int h, int kt){
    #pragma unroll
    for (int r=0;r<2;++r){
      const int rb = h*128 + r*64 + w*8;
      __builtin_amdgcn_global_load_lds(
        AS1(Abase + (size_t)(rb + (lane>>3))*1024 + kt*64),
        AS3(&Asl[buf][rb][0]), 16, 0, 0);
    }
  };
  auto stB = [&](int buf, int h, int kt){
    #pragma unroll
    for (int r=0;r<2;++r){
      const int rb = h*128 + r*64 + w*8;
      __builtin_amdgcn_global_load_lds(
        AS1(Bbase + (size_t)(rb + (lane>>3))*1024 + kt*64),
        AS3(&Bsl[buf][rb][0]), 16, 0, 0);
    }
  };
  // register subtile loads (swizzled reads, proven conflict-free pattern)
  auto ldA = [&](bf16x8* af, int buf, int mh){       // 8 x ds_read_b128
    #pragma unroll
    for (int mi=0;mi<4;++mi)
      #pragma unroll
      for (int ks=0;ks<2;++ks)
        af[mi*2+ks] = *(const bf16x8*)&Asl[buf][wm*128 + mh*64 + mi*16 + fr]
                                          [(((ks*4+fgi)^(fr&7))*8)];
  };
  auto ldB = [&](bf16x8* bq, int buf, int nh){       // 4 x ds_read_b128
    #pragma unroll
    for (int ni=0;ni<2;++ni)
      #pragma unroll
      for (int ks=0;ks<2;++ks)
        bq[ni*2+ks] = *(const bf16x8*)&Bsl[buf][wn*64 + nh*32 + ni*16 + fr]
                                           [(((ks*4+fgi)^(fr&7))*8)];
  };

#define MMAQ(AF, BF, MH, NH) do{                                             \
    __builtin_amdgcn_s_setprio(1);                                           \
    _Pragma("unroll")                                                        \
    for (int mi=0;mi<4;++mi){                                                \
      _Pragma("unroll")                                                      \
      for (int ni=0;ni<2;++ni){                                              \
        _Pragma("unroll")                                                    \
        for (int ks=0;ks<2;++ks)                                             \
          acc[(MH)*4+mi][(NH)*2+ni] = __builtin_amdgcn_mfma_f32_16x16x32_bf16( \
            (AF)[mi*2+ks], (BF)[ni*2+ks], acc[(MH)*4+mi][(NH)*2+ni], 0,0,0); \
      }}                                                                     \
    __builtin_amdgcn_s_setprio(0); }while(0)

  // prologue: buf0 <- K-tile0 (all 4 halves), buf1 <- K-tile1 B-halves
  stA(0,0,0); stA(0,1,0); stB(0,0,0); stB(0,1,0);
  stB(1,0,1); stB(1,1,1);
  asm volatile("s_waitcnt vmcnt(4)" ::: "memory");   // buf0 complete
  BARX();

  bf16x8 af[8], bq0[4], bq1[4];
  #pragma unroll 1
  for (int t=0; t<8; ++t){
    const int klo = 2*t, khi = 2*t+1;
    const bool pf = (t < 7);
    // P1: read A-mh0,B-nh0 (buf0); stage buf1-Ah0 (khi)
    ldA(af, 0, 0); ldB(bq0, 0, 0);
    stA(1, 0, khi);
    BARX(); LGKM0(); MMAQ(af, bq0, 0, 0); BARX();
    // P2: read B-nh1 (buf0); stage buf1-Ah1 (khi)
    ldB(bq1, 0, 1);
    stA(1, 1, khi);
    BARX(); LGKM0(); MMAQ(af, bq1, 0, 1); BARX();
    // P3: read A-mh1 (buf0); stage buf0-Bh0 (klo+2)
    ldA(af, 0, 1);
    if (pf) stB(0, 0, klo+2);
    BARX(); LGKM0(); MMAQ(af, bq1, 1, 1); BARX();
    // P4: regs only; stage buf0-Bh1 (klo+2); counted vmcnt covers buf1
    if (pf) stB(0, 1, klo+2);
    BARX(); MMAQ(af, bq0, 1, 0);
    if (pf) asm volatile("s_waitcnt vmcnt(4)" ::: "memory");
    else    asm volatile("s_waitcnt vmcnt(0)" ::: "memory");
    BARX();
    // P5: read A-mh0,B-nh0 (buf1); stage buf0-Ah0 (klo+2)
    ldA(af, 1, 0); ldB(bq0, 1, 0);
    if (pf) stA(0, 0, klo+2);
    BARX(); LGKM0(); MMAQ(af, bq0, 0, 0); BARX();
    // P6: read B-nh1 (buf1); stage buf0-Ah1 (klo+2)
    ldB(bq1, 1, 1);
    if (pf) stA(0, 1, klo+2);
    BARX(); LGKM0(); MMAQ(af, bq1, 0, 1); BARX();
    // P7: read A-mh1 (buf1); stage buf1-Bh0 (khi+2)
    ldA(af, 1, 1);
    if (pf) stB(1, 0, khi+2);
    BARX(); LGKM0(); MMAQ(af, bq1, 1, 1); BARX();
    // P8: regs only; stage buf1-Bh1 (khi+2); counted vmcnt covers buf0
    if (pf) stB(1, 1, khi+2);
    BARX(); MMAQ(af, bq0, 1, 0);
    if (pf) asm volatile("s_waitcnt vmcnt(4)" ::: "memory");
    BARX();
  }
#undef MMAQ

  const int cr = fgi * 4;
  if (EPI == 2 && n0 >= 1024){
    // fused V transpose via per-wave 16KB LDS tile (Asl/Bsl reuse is safe:
    // all staging drained by tail vmcnt(0), all waves past final barrier).
    __syncthreads();
    u16* eps = (w < 4) ? (&Asl[0][0][0] + w*8192) : (&Bsl[0][0][0] + (w-4)*8192);
    // scatter acc into swizzled [64 hd][128 key] tile (u16 idx ^= (hd&7)<<3)
    #pragma unroll
    for (int mf=0; mf<8; ++mf){
      const int keyb = mf*16 + cr;        // 4-aligned; XOR bits >=3 keep runs
      #pragma unroll
      for (int nf=0; nf<4; ++nf){
        const int hd = nf*16 + fr;
        u16x4 ov;
        #pragma unroll
        for (int e=0;e<4;++e) ov[e] = f2bf(acc[mf][nf][e]);
        *(u16x4*)&eps[hd*128 + (keyb ^ ((hd & 7) << 3))] = ov;
      }
    }
    const int bb = m0 >> 9;
    const int kbase = (m0 & 511) + wm*128;
    const int hdw = (n0 - 1024) + wn*64;
    u16* vTd = (u16*)Cout2;
    #pragma unroll
    for (int rr=0; rr<16; ++rr){
      const int hdl = rr*4 + (lane >> 4);
      const int kk = (lane & 15)*8;       // 8-aligned; XOR bits 3..5 safe
      u16x8 vv = *(const u16x8*)&eps[hdl*128 + (kk ^ ((hdl & 7) << 3))];
      *(u16x8*)(vTd + (size_t)(bb*1024 + hdw + hdl)*512 + kbase + kk) = vv;
    }
  } else {
    #pragma unroll
    for (int mf=0; mf<8; ++mf){
      #pragma unroll
      for (int nf=0; nf<4; ++nf){
        const int n = n0 + wn*64 + nf*16 + fr;
        #pragma unroll
        for (int e=0;e<4;++e){
          const int m = m0 + wm*128 + mf*16 + cr + e;
          float v = acc[mf][nf][e];
          if (EPI == 1){
            float r = v + bo[n];
            r = r > 0.f ? r : 0.f;
            ((float*)Cout)[(size_t)m*1024 + n] = bf2f(Xres[(size_t)m*1024 + n]) + r;
          } else {
            ((u16*)Cout)[(size_t)m*1024 + n] = f2bf(v);
          }
        }
      }
    }
  }
}

// ---------------- fused flash attention + residual (streamed K/V) ------------
// grid = B*H*2 ; block = 256 (4 waves, 64 q-rows = 2 fragments each).
// K/V streamed in 32-key slices through a depth-4 LDS ring; counted vmcnt(4)
// + raw s_barrier per step.  (256,2): VGPR 100, no spill (R14's (256,4)
// capped VGPR at 64 -> scratch spills -> FETCH 65->472MB, dur 73->170us).
__global__ __launch_bounds__(256, 2) void k_attn(const u16* __restrict__ qproj,
    const u16* __restrict__ kproj, const u16* __restrict__ vT,
    const int* __restrict__ mask, float* __restrict__ O)
{
  __shared__ alignas(16) char smem[33792];
  u16* KR = (u16*)smem;              // ring: 4 x [32 key][64 d]  (16 KB)
  u16* VR = (u16*)(smem + 16384);    // ring: 4 x [64 d][32 key]  (16 KB)
  u16* mv = (u16*)(smem + 32768);    // 512 mask bf16 values (1 KB)
  // epilogue reuses smem[0,32768): 4 waves x [32 q][64 d] f32, XOR-swizzled

  const int bidl = (int)blockIdx.x;
  const int bid = (bidl & 7) * 128 + (bidl >> 3);   // XCD-contiguous, bijective
  const int qh = bid & 1, h = (bid >> 1) & 15, b = bid >> 5;
  const int tid = threadIdx.x, lane = tid & 63, w = tid >> 6;
  const int q31 = lane & 31, hi = lane >> 5;
  const float CSC = 0.04508421990278011f;   // log2(e)/32 (pre-applied to Q)

  // mask -> bf16(-8192) table
  mv[tid]       = mask[b*512 + tid]       ? 0xC600u : 0u;
  mv[tid + 256] = mask[b*512 + 256 + tid] ? 0xC600u : 0u;
  __syncthreads();

  // per-step staging: wave w stages keys [w*8,w*8+8) of K slice and
  // d-rows [w*16,w*16+16) of V^T slice. LDS dest linear; source pre-swizzled.
  auto stage = [&](int s){
    const int r = s & 3;
    {
      const int kl = w*8 + (lane >> 3);
      const int gs = (lane & 7) ^ (kl & 7);
      __builtin_amdgcn_global_load_lds(
        AS1(kproj + (size_t)(b*512 + s*32 + kl)*1024 + h*64 + gs*8),
        AS3(KR + r*2048 + w*512), 16, 0, 0);
    }
    {
      const int d = w*16 + (lane >> 2);
      const int gs = (lane & 3) ^ ((d >> 1) & 3);
      __builtin_amdgcn_global_load_lds(
        AS1(vT + (size_t)((b*16 + h)*64 + d)*512 + s*32 + gs*8),
        AS3(VR + r*2048 + w*512), 16, 0, 0);
    }
  };

  stage(0); stage(1); stage(2);   // 6 loads in flight per wave

  // Q fragments for 2 x 32 q-rows, pre-scaled by CSC
  bf16x8 qf[2][4];
  #pragma unroll
  for (int f=0;f<2;++f){
    const int qrow = qh*256 + w*64 + f*32 + q31;
    const u16* g = qproj + (size_t)(b*512 + qrow)*1024 + h*64 + hi*8;
    #pragma unroll
    for (int ss=0;ss<4;++ss){
      u16x8 raw = *(const u16x8*)(g + ss*16);
      u32x4 sc;
      #pragma unroll
      for (int e2=0;e2<4;++e2)
        sc[e2] = pack2bf(bf2f(raw[2*e2])*CSC, bf2f(raw[2*e2+1])*CSC);
      qf[f][ss] = __builtin_bit_cast(bf16x8, sc);
    }
  }
  // Qtilde extra-slice B operand: kdim0 = 1.0 for all q columns
  u32x4 qxv = {hi ? 0u : 0x3F80u, 0u, 0u, 0u};
  const bf16x8 qx = __builtin_bit_cast(bf16x8, qxv);

  f32x16 acc0[2], acc1[2];
  #pragma unroll
  for (int hh=0;hh<2;++hh)
    #pragma unroll
    for (int r=0;r<16;++r){ acc0[hh][r] = 0.f; acc1[hh][r] = 0.f; }
  float ls0a=0.f, ls0b=0.f, ls1a=0.f, ls1b=0.f;

  auto compute = [&](int s){
    const int r = s & 3;
    const int ksw = q31 & 7;
    const u16* krow = KR + r*2048 + q31*64;
    bf16x8 kf[4];
    #pragma unroll
    for (int ss=0; ss<4; ++ss)
      kf[ss] = *(const bf16x8*)&krow[(((2*ss + hi) ^ ksw) * 8)];
    const u32 e0 = (u32)mv[s*32 + q31];
    u32x4 kxv = {hi ? 0u : e0, 0u, 0u, 0u};
    const bf16x8 kx = __builtin_bit_cast(bf16x8, kxv);

    f32x16 S0, S1;
    #pragma unroll
    for (int rr=0;rr<16;++rr){ S0[rr] = 0.f; S1[rr] = 0.f; }
    __builtin_amdgcn_s_setprio(1);
    #pragma unroll
    for (int ss=0; ss<4; ++ss)
      S0 = __builtin_amdgcn_mfma_f32_32x32x16_bf16(kf[ss], qf[0][ss], S0, 0, 0, 0);
    S0 = __builtin_amdgcn_mfma_f32_32x32x16_bf16(kx, qx, S0, 0, 0, 0);
    #pragma unroll
    for (int ss=0; ss<4; ++ss)
      S1 = __builtin_amdgcn_mfma_f32_32x32x16_bf16(kf[ss], qf[1][ss], S1, 0, 0, 0);
    S1 = __builtin_amdgcn_mfma_f32_32x32x16_bf16(kx, qx, S1, 0, 0, 0);
    __builtin_amdgcn_s_setprio(0);

    u32 w0[8], w1[8];
    #pragma unroll
    for (int i2=0;i2<8;++i2){
      const float p0 = exp2f(S0[2*i2]);
      const float p1 = exp2f(S0[2*i2+1]);
      const float p2 = exp2f(S1[2*i2]);
      const float p3 = exp2f(S1[2*i2+1]);
      if (i2 & 1){ ls0b += p0 + p1; ls1b += p2 + p3; }
      else       { ls0a += p0 + p1; ls1a += p2 + p3; }
      w0[i2] = pack2bf(p0, p1);
      w1[i2] = pack2bf(p2, p3);
    }
    pswap(w0[0], w0[2]); pswap(w0[1], w0[3]);
    pswap(w0[4], w0[6]); pswap(w0[5], w0[7]);
    pswap(w1[0], w1[2]); pswap(w1[1], w1[3]);
    pswap(w1[4], w1[6]); pswap(w1[5], w1[7]);
    u32x4 a0v = {w0[0], w0[1], w0[2], w0[3]};
    u32x4 b0v = {w0[4], w0[5], w0[6], w0[7]};
    u32x4 a1v = {w1[0], w1[1], w1[2], w1[3]};
    u32x4 b1v = {w1[4], w1[5], w1[6], w1[7]};
    const bf16x8 paA0 = __builtin_bit_cast(bf16x8, a0v);
    const bf16x8 paB0 = __builtin_bit_cast(bf16x8, b0v);
    const bf16x8 paA1 = __builtin_bit_cast(bf16x8, a1v);
    const bf16x8 paB1 = __builtin_bit_cast(bf16x8, b1v);

    __builtin_amdgcn_s_setprio(1);
    #pragma unroll
    for (int hh=0;hh<2;++hh){
      const int d = hh*32 + q31;
      const int dsw = (d >> 1) & 3;
      const u16* vrow = VR + r*2048 + d*32;
      bf16x8 vf0 = *(const bf16x8*)&vrow[((hi ^ dsw) * 8)];
      bf16x8 vf1 = *(const bf16x8*)&vrow[(((2 + hi) ^ dsw) * 8)];
      acc0[hh] = __builtin_amdgcn_mfma_f32_32x32x16_bf16(vf0, paA0, acc0[hh], 0, 0, 0);
      acc0[hh] = __builtin_amdgcn_mfma_f32_32x32x16_bf16(vf1, paB0, acc0[hh], 0, 0, 0);
      acc1[hh] = __builtin_amdgcn_mfma_f32_32x32x16_bf16(vf0, paA1, acc1[hh], 0, 0, 0);
      acc1[hh] = __builtin_amdgcn_mfma_f32_32x32x16_bf16(vf1, paB1, acc1[hh], 0, 0, 0);
    }
    __builtin_amdgcn_s_setprio(0);
  };

  // main loop: counted vmcnt, stage(s+3) issued AFTER the barrier so the
  // ring slot (s+3)&3 == (s-1)&3 is provably done being read by all waves.
  #pragma unroll 1
  for (int s=0; s<14; ++s){
    asm volatile("s_waitcnt vmcnt(4)" ::: "memory");
    __builtin_amdgcn_s_barrier();
    if (s < 13) stage(s+3);
    compute(s);
  }
  asm volatile("s_waitcnt vmcnt(2)" ::: "memory");
  __builtin_amdgcn_s_barrier();
  compute(14);
  asm volatile("s_waitcnt vmcnt(0)" ::: "memory");
  __builtin_amdgcn_s_barrier();
  compute(15);

  float l0 = ls0a + ls0b;  l0 += __shfl_xor(l0, 32, 64);
  float l1 = ls1a + ls1b;  l1 += __shfl_xor(l1, 32, 64);
  const float i0 = 1.0f / l0, i1 = 1.0f / l1;

  __syncthreads();   // all waves done with KR/VR before epilogue reuse

  // epilogue: XOR-swizzled [32 q][16 granule] f32 tile per wave; store phase
  // writes one full 64B sector per row per instruction (4 lanes x 16B).
  auto epi = [&](const f32x16* accp, float inv, int f){
    float* t = (float*)smem + w*2048;
    #pragma unroll
    for (int hh=0; hh<2; ++hh)
      #pragma unroll
      for (int rq=0; rq<4; ++rq){
        const int g = (2*rq + hi + 8*hh) ^ (q31 & 15);
        f32x4 v4;
        #pragma unroll
        for (int e=0;e<4;++e) v4[e] = accp[hh][rq*4 + e] * inv;
        *(f32x4*)&t[(q31*16 + g)*4] = v4;
      }
    __syncthreads();
    const int row16 = lane >> 2, c4 = lane & 3;
    #pragma unroll
    for (int rr=0; rr<2; ++rr){
      const int q = rr*16 + row16;
      const int grow = qh*256 + w*64 + f*32 + q;
      const size_t gbase = (size_t)(b*512 + grow)*1024 + h*64;
      #pragma unroll
      for (int j=0; j<4; ++j){
        const int g = (j*4 + c4) ^ (q & 15);
        f32x4 v4 = *(const f32x4*)&t[(q*16 + g)*4];
        u16x4 qres = *(const u16x4*)(qproj + gbase + j*16 + c4*4);
        f32x4 o4;
        #pragma unroll
        for (int e=0;e<4;++e) o4[e] = v4[e] + bf2f(qres[e]);
        *(f32x4*)(O + gbase + j*16 + c4*4) = o4;
      }
    }
    __syncthreads();
  };
  epi(acc0, i0, 0);
  epi(acc1, i1, 1);
}

// ---------------- LayerNorm: one wave per row, 4 rows per block --------------
template<int OUT_BF16>
__global__ __launch_bounds__(256) void k_ln(const float* __restrict__ X,
    const float* __restrict__ gam, const float* __restrict__ bet,
    void* __restrict__ out)
{
  const int row = blockIdx.x*4 + (threadIdx.x >> 6);
  const int lane = threadIdx.x & 63;
  const float* xr = X + (size_t)row*1024 + lane*4;
  f32x4 v[4];
  float s = 0.f, ss = 0.f;
  #pragma unroll
  for (int j=0;j<4;++j){
    v[j] = *(const f32x4*)(xr + j*256);
    #pragma unroll
    for (int e=0;e<4;++e){ s += v[j][e]; ss += v[j][e]*v[j][e]; }
  }
  #pragma unroll
  for (int o=32; o>0; o>>=1){ s += __shfl_xor(s, o, 64); ss += __shfl_xor(ss, o, 64); }
  const float mu  = s * 0.0009765625f;
  const float var = ss * 0.0009765625f - mu*mu;
  const float rs  = rsqrtf(var + 1e-5f);
  #pragma unroll
  for (int j=0;j<4;++j){
    f32x4 gg = *(const f32x4*)(gam + j*256 + lane*4);
    f32x4 bb = *(const f32x4*)(bet + j*256 + lane*4);
    f32x4 o;
    #pragma unroll
    for (int e=0;e<4;++e) o[e] = (v[j][e]-mu)*rs*gg[e] + bb[e];
    if (OUT_BF16){
      u16x4 ob;
      #pragma unroll
      for (int e=0;e<4;++e) ob[e] = f2bf(o[e]);
      *(u16x4*)((u16*)out + (size_t)row*1024 + j*256 + lane*4) = ob;
    } else {
      *(f32x4*)((float*)out + (size_t)row*1024 + j*256 + lane*4) = o;
    }
  }
}

// ---------------- launch -----------------------------------------------------
extern "C" void kernel_launch(void* const* d_in, const int* in_sizes, int n_in,
                              void* d_out, int out_size, void* d_ws, size_t ws_size,
                              hipStream_t stream)
{
  const float* Q  = (const float*)d_in[0];
  const float* K  = (const float*)d_in[1];
  const int*   Mk = (const int*)d_in[2];
  const float* Wq = (const float*)d_in[3];
  const float* Wk = (const float*)d_in[4];
  const float* Wv = (const float*)d_in[5];
  const float* Wo = (const float*)d_in[6];
  const float* bo = (const float*)d_in[7];
  const float* g0 = (const float*)d_in[8];
  const float* b0 = (const float*)d_in[9];
  const float* g1 = (const float*)d_in[10];
  const float* b1 = (const float*)d_in[11];

  char* ws = (char*)d_ws;
  u16* qproj = (u16*)(ws);
  u16* kproj = (u16*)(ws + 33554432u);
  u16* Qb    = (u16*)(ws + 100663296u);
  u16* vTb   = (u16*)(ws + 100663296u);   // reuses Qb after GEMM-q
  u16* Kb    = (u16*)(ws + 134217728u);
  u16* Wb    = (u16*)(ws + 167772160u);
  u16* Xln   = qproj;                      // reuses qproj after attention
  float* Yb  = (float*)(ws + 33554432u);   // reuses kproj region after attention
  float* Ob  = (float*)d_out;              // pre-LN0 O lives in d_out

  k_cast_qk<<<dim3(8192,2),256,0,stream>>>(Q, K, Qb, Kb);
  k_cast_w <<<dim3(512,4), 256,0,stream>>>(Wq, Wk, Wv, Wo, Wb);
  k_gemm8<0><<<256,512,0,stream>>>(Qb, Wb, (void*)qproj, nullptr, nullptr, nullptr);
  k_gemm8<2><<<512,512,0,stream>>>(Kb, Wb + 1048576, (void*)kproj, (void*)vTb, nullptr, nullptr);
  k_attn   <<<1024,256,0,stream>>>(qproj, kproj, vTb, Mk, Ob);
  k_ln<1>  <<<4096,256,0,stream>>>(Ob, g0, b0, (void*)Xln);
  k_gemm8<1><<<256,512,0,stream>>>(Xln, Wb + 3145728, (void*)Yb, nullptr, Xln, bo);
  k_ln<0>  <<<4096,256,0,stream>>>(Yb, g1, b1, d_out);
}

// Round 16
// 277.933 us; speedup vs baseline: 1.4670x; 1.0431x over previous
//
#include <hip/hip_runtime.h>
#include <stdint.h>

typedef unsigned short u16;
typedef unsigned int   u32;
typedef __bf16 bf16x8 __attribute__((ext_vector_type(8)));
typedef __bf16 bf16x2 __attribute__((ext_vector_type(2)));
typedef float  f32x4  __attribute__((ext_vector_type(4)));
typedef float  f32x16 __attribute__((ext_vector_type(16)));
typedef u16    u16x4  __attribute__((ext_vector_type(4)));
typedef u16    u16x8  __attribute__((ext_vector_type(8)));
typedef u32    u32x4  __attribute__((ext_vector_type(4)));

#define DEV __device__ __forceinline__
#define AS1(p) ((const __attribute__((address_space(1))) void*)(p))
#define AS3(p) ((__attribute__((address_space(3))) void*)(p))

DEV u16 f2bf(float f){ return __builtin_bit_cast(u16, (__bf16)f); }
DEV float bf2f(u16 h){ return __uint_as_float(((u32)h) << 16); }
DEV u32 pack2bf(float a, float b){
  bf16x2 t; t[0] = (__bf16)a; t[1] = (__bf16)b;
  return __builtin_bit_cast(u32, t);
}
// v_permlane32_swap_b32: a.hi <-> b.lo  (gfx950)
DEV void pswap(u32 &a, u32 &b){
  asm volatile("v_permlane32_swap_b32 %0, %1" : "+v"(a), "+v"(b));
}

#define BARX() __builtin_amdgcn_s_barrier()
#define LGKM0() do{ asm volatile("s_waitcnt lgkmcnt(0)" ::: "memory"); \
                    __builtin_amdgcn_sched_barrier(0); }while(0)

// ---------------- cast kernels ----------------
__global__ __launch_bounds__(256) void k_cast_qk(const float* __restrict__ Q,
    const float* __restrict__ K, u16* __restrict__ Qb, u16* __restrict__ Kb){
  const float* s = blockIdx.y ? K : Q;
  u16* d = blockIdx.y ? Kb : Qb;
  size_t i = ((size_t)blockIdx.x * 256 + threadIdx.x) * 8;
  f32x4 a = *(const f32x4*)(s + i);
  f32x4 b = *(const f32x4*)(s + i + 4);
  u16x8 o;
  o[0]=f2bf(a[0]); o[1]=f2bf(a[1]); o[2]=f2bf(a[2]); o[3]=f2bf(a[3]);
  o[4]=f2bf(b[0]); o[5]=f2bf(b[1]); o[6]=f2bf(b[2]); o[7]=f2bf(b[3]);
  *(u16x8*)(d + i) = o;
}

__global__ __launch_bounds__(256) void k_cast_w(const float* __restrict__ W0,
    const float* __restrict__ W1, const float* __restrict__ W2,
    const float* __restrict__ W3, u16* __restrict__ dst){
  const float* s = (blockIdx.y == 0) ? W0 : (blockIdx.y == 1) ? W1 :
                   (blockIdx.y == 2) ? W2 : W3;
  size_t i = ((size_t)blockIdx.x * 256 + threadIdx.x) * 8;
  u16* d = dst + (size_t)blockIdx.y * 1048576u + i;
  f32x4 a = *(const f32x4*)(s + i);
  f32x4 b = *(const f32x4*)(s + i + 4);
  u16x8 o;
  o[0]=f2bf(a[0]); o[1]=f2bf(a[1]); o[2]=f2bf(a[2]); o[3]=f2bf(a[3]);
  o[4]=f2bf(b[0]); o[5]=f2bf(b[1]); o[6]=f2bf(b[2]); o[7]=f2bf(b[3]);
  *(u16x8*)d = o;
}

// ---------------- GEMM (256x256 tile, 8-phase, counted vmcnt) ----------------
// C[m,n] = sum_k A[m,k]*W[n,k].  8 waves (2M x 4N), BK=64, 2 K-tiles/iter.
// EPI=0: bf16 out N=1024. EPI=1: bf16 relu+bias+residual (Y=Xres+relu(acc+bo)).
// EPI=2: N=2048 dual: n<1024 -> kproj[m][n]; n>=1024 -> fused V transpose via
//   per-wave LDS staging tile -> contiguous 256B-row stores to vT.
template<int EPI>
__global__ __launch_bounds__(512, 2) void k_gemm8(const u16* __restrict__ A,
    const u16* __restrict__ Bw, void* __restrict__ Cout, void* __restrict__ Cout2,
    const u16* __restrict__ Xres, const float* __restrict__ bo)
{
  __shared__ u16 Asl[2][256][64];
  __shared__ u16 Bsl[2][256][64];
  const int tid = threadIdx.x, lane = tid & 63, w = tid >> 6;
  const int wm = w >> 2, wn = w & 3;
  constexpr int NT = (EPI == 2) ? 8 : 4;
  const int bid = blockIdx.x;
  const int xcd = bid & 7, jt = bid >> 3;
  const int m0 = (xcd*8 + jt/NT) * 256;
  const int n0 = (jt%NT) * 256;
  const int fr = lane & 15, fgi = lane >> 4;
  const int sgs = (lane & 7) ^ (lane >> 3);     // pre-swizzled source granule
  const u16* Abase = A  + (size_t)m0*1024 + sgs*8;
  const u16* Bbase = Bw + (size_t)n0*1024 + sgs*8;

  f32x4 acc[8][4];
  #pragma unroll
  for (int i=0;i<8;++i)
    #pragma unroll
    for (int q=0;q<4;++q)
      #pragma unroll
      for (int e=0;e<4;++e) acc[i][q][e] = 0.f;

  // stage one half-tile (128 rows x 64 cols = 2 loads/thread), LDS dest linear
  auto stA = [&](int buf, int h, int kt){
    #pragma unroll
    for (int r=0;r<2;++r){
      const int rb = h*128 + r*64 + w*8;
      __builtin_amdgcn_global_load_lds(
        AS1(Abase + (size_t)(rb + (lane>>3))*1024 + kt*64),
        AS3(&Asl[buf][rb][0]), 16, 0, 0);
    }
  };
  auto stB = [&](int buf, int h, int kt){
    #pragma unroll
    for (int r=0;r<2;++r){
      const int rb = h*128 + r*64 + w*8;
      __builtin_amdgcn_global_load_lds(
        AS1(Bbase + (size_t)(rb + (lane>>3))*1024 + kt*64),
        AS3(&Bsl[buf][rb][0]), 16, 0, 0);
    }
  };
  // register subtile loads (swizzled reads, proven conflict-free pattern)
  auto ldA = [&](bf16x8* af, int buf, int mh){       // 8 x ds_read_b128
    #pragma unroll
    for (int mi=0;mi<4;++mi)
      #pragma unroll
      for (int ks=0;ks<2;++ks)
        af[mi*2+ks] = *(const bf16x8*)&Asl[buf][wm*128 + mh*64 + mi*16 + fr]
                                          [(((ks*4+fgi)^(fr&7))*8)];
  };
  auto ldB = [&](bf16x8* bq, int buf, int nh){       // 4 x ds_read_b128
    #pragma unroll
    for (int ni=0;ni<2;++ni)
      #pragma unroll
      for (int ks=0;ks<2;++ks)
        bq[ni*2+ks] = *(const bf16x8*)&Bsl[buf][wn*64 + nh*32 + ni*16 + fr]
                                           [(((ks*4+fgi)^(fr&7))*8)];
  };

#define MMAQ(AF, BF, MH, NH) do{                                             \
    __builtin_amdgcn_s_setprio(1);                                           \
    _Pragma("unroll")                                                        \
    for (int mi=0;mi<4;++mi){                                                \
      _Pragma("unroll")                                                      \
      for (int ni=0;ni<2;++ni){                                              \
        _Pragma("unroll")                                                    \
        for (int ks=0;ks<2;++ks)                                             \
          acc[(MH)*4+mi][(NH)*2+ni] = __builtin_amdgcn_mfma_f32_16x16x32_bf16( \
            (AF)[mi*2+ks], (BF)[ni*2+ks], acc[(MH)*4+mi][(NH)*2+ni], 0,0,0); \
      }}                                                                     \
    __builtin_amdgcn_s_setprio(0); }while(0)

  // prologue: buf0 <- K-tile0 (all 4 halves), buf1 <- K-tile1 B-halves
  stA(0,0,0); stA(0,1,0); stB(0,0,0); stB(0,1,0);
  stB(1,0,1); stB(1,1,1);
  asm volatile("s_waitcnt vmcnt(4)" ::: "memory");   // buf0 complete
  BARX();

  bf16x8 af[8], bq0[4], bq1[4];
  #pragma unroll 1
  for (int t=0; t<8; ++t){
    const int klo = 2*t, khi = 2*t+1;
    const bool pf = (t < 7);
    // P1: read A-mh0,B-nh0 (buf0); stage buf1-Ah0 (khi)
    ldA(af, 0, 0); ldB(bq0, 0, 0);
    stA(1, 0, khi);
    BARX(); LGKM0(); MMAQ(af, bq0, 0, 0); BARX();
    // P2: read B-nh1 (buf0); stage buf1-Ah1 (khi)
    ldB(bq1, 0, 1);
    stA(1, 1, khi);
    BARX(); LGKM0(); MMAQ(af, bq1, 0, 1); BARX();
    // P3: read A-mh1 (buf0); stage buf0-Bh0 (klo+2)
    ldA(af, 0, 1);
    if (pf) stB(0, 0, klo+2);
    BARX(); LGKM0(); MMAQ(af, bq1, 1, 1); BARX();
    // P4: regs only; stage buf0-Bh1 (klo+2); counted vmcnt covers buf1
    if (pf) stB(0, 1, klo+2);
    BARX(); MMAQ(af, bq0, 1, 0);
    if (pf) asm volatile("s_waitcnt vmcnt(4)" ::: "memory");
    else    asm volatile("s_waitcnt vmcnt(0)" ::: "memory");
    BARX();
    // P5: read A-mh0,B-nh0 (buf1); stage buf0-Ah0 (klo+2)
    ldA(af, 1, 0); ldB(bq0, 1, 0);
    if (pf) stA(0, 0, klo+2);
    BARX(); LGKM0(); MMAQ(af, bq0, 0, 0); BARX();
    // P6: read B-nh1 (buf1); stage buf0-Ah1 (klo+2)
    ldB(bq1, 1, 1);
    if (pf) stA(0, 1, klo+2);
    BARX(); LGKM0(); MMAQ(af, bq1, 0, 1); BARX();
    // P7: read A-mh1 (buf1); stage buf1-Bh0 (khi+2)
    ldA(af, 1, 1);
    if (pf) stB(1, 0, khi+2);
    BARX(); LGKM0(); MMAQ(af, bq1, 1, 1); BARX();
    // P8: regs only; stage buf1-Bh1 (khi+2); counted vmcnt covers buf0
    if (pf) stB(1, 1, khi+2);
    BARX(); MMAQ(af, bq0, 1, 0);
    if (pf) asm volatile("s_waitcnt vmcnt(4)" ::: "memory");
    BARX();
  }
#undef MMAQ

  const int cr = fgi * 4;
  if (EPI == 2 && n0 >= 1024){
    // fused V transpose via per-wave 16KB LDS tile (Asl/Bsl reuse is safe:
    // all staging drained by tail vmcnt(0), all waves past final barrier).
    __syncthreads();
    u16* eps = (w < 4) ? (&Asl[0][0][0] + w*8192) : (&Bsl[0][0][0] + (w-4)*8192);
    // scatter acc into swizzled [64 hd][128 key] tile (u16 idx ^= (hd&7)<<3)
    #pragma unroll
    for (int mf=0; mf<8; ++mf){
      const int keyb = mf*16 + cr;        // 4-aligned; XOR bits >=3 keep runs
      #pragma unroll
      for (int nf=0; nf<4; ++nf){
        const int hd = nf*16 + fr;
        u16x4 ov;
        #pragma unroll
        for (int e=0;e<4;++e) ov[e] = f2bf(acc[mf][nf][e]);
        *(u16x4*)&eps[hd*128 + (keyb ^ ((hd & 7) << 3))] = ov;
      }
    }
    const int bb = m0 >> 9;
    const int kbase = (m0 & 511) + wm*128;
    const int hdw = (n0 - 1024) + wn*64;
    u16* vTd = (u16*)Cout2;
    #pragma unroll
    for (int rr=0; rr<16; ++rr){
      const int hdl = rr*4 + (lane >> 4);
      const int kk = (lane & 15)*8;       // 8-aligned; XOR bits 3..5 safe
      u16x8 vv = *(const u16x8*)&eps[hdl*128 + (kk ^ ((hdl & 7) << 3))];
      *(u16x8*)(vTd + (size_t)(bb*1024 + hdw + hdl)*512 + kbase + kk) = vv;
    }
  } else {
    #pragma unroll
    for (int mf=0; mf<8; ++mf){
      #pragma unroll
      for (int nf=0; nf<4; ++nf){
        const int n = n0 + wn*64 + nf*16 + fr;
        #pragma unroll
        for (int e=0;e<4;++e){
          const int m = m0 + wm*128 + mf*16 + cr + e;
          float v = acc[mf][nf][e];
          if (EPI == 1){
            float r = v + bo[n];
            r = r > 0.f ? r : 0.f;
            ((u16*)Cout)[(size_t)m*1024 + n] =
              f2bf(bf2f(Xres[(size_t)m*1024 + n]) + r);
          } else {
            ((u16*)Cout)[(size_t)m*1024 + n] = f2bf(v);
          }
        }
      }
    }
  }
}

// ---------------- fused flash attention + residual (streamed K/V) ------------
// grid = B*H*2 ; block = 256 (4 waves, 64 q-rows = 2 fragments each).
// K/V streamed in 32-key slices through a depth-4 LDS ring; counted vmcnt(4)
// + raw s_barrier per step.  (256,2): VGPR ~116, no spill.  fzero is a
// loop-invariant zero C-operand: kills 64 v_mov/step of S-init.
// Output O is bf16 (feeds LN0; bf16 round << absmax margin).
__global__ __launch_bounds__(256, 2) void k_attn(const u16* __restrict__ qproj,
    const u16* __restrict__ kproj, const u16* __restrict__ vT,
    const int* __restrict__ mask, u16* __restrict__ O)
{
  __shared__ alignas(16) char smem[33792];
  u16* KR = (u16*)smem;              // ring: 4 x [32 key][64 d]  (16 KB)
  u16* VR = (u16*)(smem + 16384);    // ring: 4 x [64 d][32 key]  (16 KB)
  u16* mv = (u16*)(smem + 32768);    // 512 mask bf16 values (1 KB)
  // epilogue reuses smem[0,32768): 4 waves x [32 q][64 d] f32, XOR-swizzled

  const int bidl = (int)blockIdx.x;
  const int bid = (bidl & 7) * 128 + (bidl >> 3);   // XCD-contiguous, bijective
  const int qh = bid & 1, h = (bid >> 1) & 15, b = bid >> 5;
  const int tid = threadIdx.x, lane = tid & 63, w = tid >> 6;
  const int q31 = lane & 31, hi = lane >> 5;
  const float CSC = 0.04508421990278011f;   // log2(e)/32 (pre-applied to Q)

  // mask -> bf16(-8192) table
  mv[tid]       = mask[b*512 + tid]       ? 0xC600u : 0u;
  mv[tid + 256] = mask[b*512 + 256 + tid] ? 0xC600u : 0u;
  __syncthreads();

  // per-step staging: wave w stages keys [w*8,w*8+8) of K slice and
  // d-rows [w*16,w*16+16) of V^T slice. LDS dest linear; source pre-swizzled.
  auto stage = [&](int s){
    const int r = s & 3;
    {
      const int kl = w*8 + (lane >> 3);
      const int gs = (lane & 7) ^ (kl & 7);
      __builtin_amdgcn_global_load_lds(
        AS1(kproj + (size_t)(b*512 + s*32 + kl)*1024 + h*64 + gs*8),
        AS3(KR + r*2048 + w*512), 16, 0, 0);
    }
    {
      const int d = w*16 + (lane >> 2);
      const int gs = (lane & 3) ^ ((d >> 1) & 3);
      __builtin_amdgcn_global_load_lds(
        AS1(vT + (size_t)((b*16 + h)*64 + d)*512 + s*32 + gs*8),
        AS3(VR + r*2048 + w*512), 16, 0, 0);
    }
  };

  stage(0); stage(1); stage(2);   // 6 loads in flight per wave

  // Q fragments for 2 x 32 q-rows, pre-scaled by CSC
  bf16x8 qf[2][4];
  #pragma unroll
  for (int f=0;f<2;++f){
    const int qrow = qh*256 + w*64 + f*32 + q31;
    const u16* g = qproj + (size_t)(b*512 + qrow)*1024 + h*64 + hi*8;
    #pragma unroll
    for (int ss=0;ss<4;++ss){
      u16x8 raw = *(const u16x8*)(g + ss*16);
      u32x4 sc;
      #pragma unroll
      for (int e2=0;e2<4;++e2)
        sc[e2] = pack2bf(bf2f(raw[2*e2])*CSC, bf2f(raw[2*e2+1])*CSC);
      qf[f][ss] = __builtin_bit_cast(bf16x8, sc);
    }
  }
  // Qtilde extra-slice B operand: kdim0 = 1.0 for all q columns
  u32x4 qxv = {hi ? 0u : 0x3F80u, 0u, 0u, 0u};
  const bf16x8 qx = __builtin_bit_cast(bf16x8, qxv);

  // loop-invariant zero C-operand for the first MFMA of each S chain
  f32x16 fzero;
  #pragma unroll
  for (int r=0;r<16;++r) fzero[r] = 0.f;

  f32x16 acc0[2], acc1[2];
  #pragma unroll
  for (int hh=0;hh<2;++hh)
    #pragma unroll
    for (int r=0;r<16;++r){ acc0[hh][r] = 0.f; acc1[hh][r] = 0.f; }
  float ls0a=0.f, ls0b=0.f, ls1a=0.f, ls1b=0.f;

  auto compute = [&](int s){
    const int r = s & 3;
    const int ksw = q31 & 7;
    const u16* krow = KR + r*2048 + q31*64;
    bf16x8 kf[4];
    #pragma unroll
    for (int ss=0; ss<4; ++ss)
      kf[ss] = *(const bf16x8*)&krow[(((2*ss + hi) ^ ksw) * 8)];
    const u32 e0 = (u32)mv[s*32 + q31];
    u32x4 kxv = {hi ? 0u : e0, 0u, 0u, 0u};
    const bf16x8 kx = __builtin_bit_cast(bf16x8, kxv);

    __builtin_amdgcn_s_setprio(1);
    f32x16 S0 = __builtin_amdgcn_mfma_f32_32x32x16_bf16(kf[0], qf[0][0], fzero, 0, 0, 0);
    #pragma unroll
    for (int ss=1; ss<4; ++ss)
      S0 = __builtin_amdgcn_mfma_f32_32x32x16_bf16(kf[ss], qf[0][ss], S0, 0, 0, 0);
    S0 = __builtin_amdgcn_mfma_f32_32x32x16_bf16(kx, qx, S0, 0, 0, 0);
    f32x16 S1 = __builtin_amdgcn_mfma_f32_32x32x16_bf16(kf[0], qf[1][0], fzero, 0, 0, 0);
    #pragma unroll
    for (int ss=1; ss<4; ++ss)
      S1 = __builtin_amdgcn_mfma_f32_32x32x16_bf16(kf[ss], qf[1][ss], S1, 0, 0, 0);
    S1 = __builtin_amdgcn_mfma_f32_32x32x16_bf16(kx, qx, S1, 0, 0, 0);
    __builtin_amdgcn_s_setprio(0);

    u32 w0[8], w1[8];
    #pragma unroll
    for (int i2=0;i2<8;++i2){
      const float p0 = exp2f(S0[2*i2]);
      const float p1 = exp2f(S0[2*i2+1]);
      const float p2 = exp2f(S1[2*i2]);
      const float p3 = exp2f(S1[2*i2+1]);
      if (i2 & 1){ ls0b += p0 + p1; ls1b += p2 + p3; }
      else       { ls0a += p0 + p1; ls1a += p2 + p3; }
      w0[i2] = pack2bf(p0, p1);
      w1[i2] = pack2bf(p2, p3);
    }
    pswap(w0[0], w0[2]); pswap(w0[1], w0[3]);
    pswap(w0[4], w0[6]); pswap(w0[5], w0[7]);
    pswap(w1[0], w1[2]); pswap(w1[1], w1[3]);
    pswap(w1[4], w1[6]); pswap(w1[5], w1[7]);
    u32x4 a0v = {w0[0], w0[1], w0[2], w0[3]};
    u32x4 b0v = {w0[4], w0[5], w0[6], w0[7]};
    u32x4 a1v = {w1[0], w1[1], w1[2], w1[3]};
    u32x4 b1v = {w1[4], w1[5], w1[6], w1[7]};
    const bf16x8 paA0 = __builtin_bit_cast(bf16x8, a0v);
    const bf16x8 paB0 = __builtin_bit_cast(bf16x8, b0v);
    const bf16x8 paA1 = __builtin_bit_cast(bf16x8, a1v);
    const bf16x8 paB1 = __builtin_bit_cast(bf16x8, b1v);

    __builtin_amdgcn_s_setprio(1);
    #pragma unroll
    for (int hh=0;hh<2;++hh){
      const int d = hh*32 + q31;
      const int dsw = (d >> 1) & 3;
      const u16* vrow = VR + r*2048 + d*32;
      bf16x8 vf0 = *(const bf16x8*)&vrow[((hi ^ dsw) * 8)];
      bf16x8 vf1 = *(const bf16x8*)&vrow[(((2 + hi) ^ dsw) * 8)];
      acc0[hh] = __builtin_amdgcn_mfma_f32_32x32x16_bf16(vf0, paA0, acc0[hh], 0, 0, 0);
      acc0[hh] = __builtin_amdgcn_mfma_f32_32x32x16_bf16(vf1, paB0, acc0[hh], 0, 0, 0);
      acc1[hh] = __builtin_amdgcn_mfma_f32_32x32x16_bf16(vf0, paA1, acc1[hh], 0, 0, 0);
      acc1[hh] = __builtin_amdgcn_mfma_f32_32x32x16_bf16(vf1, paB1, acc1[hh], 0, 0, 0);
    }
    __builtin_amdgcn_s_setprio(0);
  };

  // main loop: counted vmcnt, stage(s+3) issued AFTER the barrier so the
  // ring slot (s+3)&3 == (s-1)&3 is provably done being read by all waves.
  #pragma unroll 1
  for (int s=0; s<14; ++s){
    asm volatile("s_waitcnt vmcnt(4)" ::: "memory");
    __builtin_amdgcn_s_barrier();
    if (s < 13) stage(s+3);
    compute(s);
  }
  asm volatile("s_waitcnt vmcnt(2)" ::: "memory");
  __builtin_amdgcn_s_barrier();
  compute(14);
  asm volatile("s_waitcnt vmcnt(0)" ::: "memory");
  __builtin_amdgcn_s_barrier();
  compute(15);

  float l0 = ls0a + ls0b;  l0 += __shfl_xor(l0, 32, 64);
  float l1 = ls1a + ls1b;  l1 += __shfl_xor(l1, 32, 64);
  const float i0 = 1.0f / l0, i1 = 1.0f / l1;

  __syncthreads();   // all waves done with KR/VR before epilogue reuse

  // epilogue: XOR-swizzled [32 q][16 granule] f32 tile per wave; store phase
  // writes bf16 rows (residual add fused), 8B/lane coalesced.
  auto epi = [&](const f32x16* accp, float inv, int f){
    float* t = (float*)smem + w*2048;
    #pragma unroll
    for (int hh=0; hh<2; ++hh)
      #pragma unroll
      for (int rq=0; rq<4; ++rq){
        const int g = (2*rq + hi + 8*hh) ^ (q31 & 15);
        f32x4 v4;
        #pragma unroll
        for (int e=0;e<4;++e) v4[e] = accp[hh][rq*4 + e] * inv;
        *(f32x4*)&t[(q31*16 + g)*4] = v4;
      }
    __syncthreads();
    const int row16 = lane >> 2, c4 = lane & 3;
    #pragma unroll
    for (int rr=0; rr<2; ++rr){
      const int q = rr*16 + row16;
      const int grow = qh*256 + w*64 + f*32 + q;
      const size_t gbase = (size_t)(b*512 + grow)*1024 + h*64;
      #pragma unroll
      for (int j=0; j<4; ++j){
        const int g = (j*4 + c4) ^ (q & 15);
        f32x4 v4 = *(const f32x4*)&t[(q*16 + g)*4];
        u16x4 qres = *(const u16x4*)(qproj + gbase + j*16 + c4*4);
        u16x4 ob;
        #pragma unroll
        for (int e=0;e<4;++e) ob[e] = f2bf(v4[e] + bf2f(qres[e]));
        *(u16x4*)(O + gbase + j*16 + c4*4) = ob;
      }
    }
    __syncthreads();
  };
  epi(acc0, i0, 0);
  epi(acc1, i1, 1);
}

// ---------------- LayerNorm: one wave per row, 4 rows per block --------------
template<int IN_BF16, int OUT_BF16>
__global__ __launch_bounds__(256) void k_ln(const void* __restrict__ Xv,
    const float* __restrict__ gam, const float* __restrict__ bet,
    void* __restrict__ out)
{
  const int row = blockIdx.x*4 + (threadIdx.x >> 6);
  const int lane = threadIdx.x & 63;
  f32x4 v[4];
  float s = 0.f, ss = 0.f;
  #pragma unroll
  for (int j=0;j<4;++j){
    if (IN_BF16){
      u16x4 rv = *(const u16x4*)((const u16*)Xv + (size_t)row*1024 + j*256 + lane*4);
      #pragma unroll
      for (int e=0;e<4;++e) v[j][e] = bf2f(rv[e]);
    } else {
      v[j] = *(const f32x4*)((const float*)Xv + (size_t)row*1024 + j*256 + lane*4);
    }
    #pragma unroll
    for (int e=0;e<4;++e){ s += v[j][e]; ss += v[j][e]*v[j][e]; }
  }
  #pragma unroll
  for (int o=32; o>0; o>>=1){ s += __shfl_xor(s, o, 64); ss += __shfl_xor(ss, o, 64); }
  const float mu  = s * 0.0009765625f;
  const float var = ss * 0.0009765625f - mu*mu;
  const float rs  = rsqrtf(var + 1e-5f);
  #pragma unroll
  for (int j=0;j<4;++j){
    f32x4 gg = *(const f32x4*)(gam + j*256 + lane*4);
    f32x4 bb = *(const f32x4*)(bet + j*256 + lane*4);
    f32x4 o;
    #pragma unroll
    for (int e=0;e<4;++e) o[e] = (v[j][e]-mu)*rs*gg[e] + bb[e];
    if (OUT_BF16){
      u16x4 ob;
      #pragma unroll
      for (int e=0;e<4;++e) ob[e] = f2bf(o[e]);
      *(u16x4*)((u16*)out + (size_t)row*1024 + j*256 + lane*4) = ob;
    } else {
      *(f32x4*)((float*)out + (size_t)row*1024 + j*256 + lane*4) = o;
    }
  }
}

// ---------------- launch -----------------------------------------------------
extern "C" void kernel_launch(void* const* d_in, const int* in_sizes, int n_in,
                              void* d_out, int out_size, void* d_ws, size_t ws_size,
                              hipStream_t stream)
{
  const float* Q  = (const float*)d_in[0];
  const float* K  = (const float*)d_in[1];
  const int*   Mk = (const int*)d_in[2];
  const float* Wq = (const float*)d_in[3];
  const float* Wk = (const float*)d_in[4];
  const float* Wv = (const float*)d_in[5];
  const float* Wo = (const float*)d_in[6];
  const float* bo = (const float*)d_in[7];
  const float* g0 = (const float*)d_in[8];
  const float* b0 = (const float*)d_in[9];
  const float* g1 = (const float*)d_in[10];
  const float* b1 = (const float*)d_in[11];

  char* ws = (char*)d_ws;
  u16* qproj = (u16*)(ws);                 // [0,32M)
  u16* kproj = (u16*)(ws + 33554432u);     // [32M,64M)
  u16* Ob16  = (u16*)(ws + 67108864u);     // [64M,96M)  attn out, bf16
  u16* Qb    = (u16*)(ws + 100663296u);
  u16* vTb   = (u16*)(ws + 100663296u);    // reuses Qb after GEMM-q
  u16* Kb    = (u16*)(ws + 134217728u);
  u16* Wb    = (u16*)(ws + 167772160u);
  u16* Xln   = qproj;                      // reuses qproj after attention
  u16* Yb16  = kproj;                      // reuses kproj after attention

  k_cast_qk<<<dim3(8192,2),256,0,stream>>>(Q, K, Qb, Kb);
  k_cast_w <<<dim3(512,4), 256,0,stream>>>(Wq, Wk, Wv, Wo, Wb);
  k_gemm8<0><<<256,512,0,stream>>>(Qb, Wb, (void*)qproj, nullptr, nullptr, nullptr);
  k_gemm8<2><<<512,512,0,stream>>>(Kb, Wb + 1048576, (void*)kproj, (void*)vTb, nullptr, nullptr);
  k_attn   <<<1024,256,0,stream>>>(qproj, kproj, vTb, Mk, Ob16);
  k_ln<1,1><<<4096,256,0,stream>>>((const void*)Ob16, g0, b0, (void*)Xln);
  k_gemm8<1><<<256,512,0,stream>>>(Xln, Wb + 3145728, (void*)Yb16, nullptr, Xln, bo);
  k_ln<1,0><<<4096,256,0,stream>>>((const void*)Yb16, g1, b1, d_out);
}